// Round 2
// baseline (89.105 us; speedup 1.0000x reference)
//
#include <hip/hip_runtime.h>
#include <cmath>

#define T_STEPS 384
#define CH 64
#define NCH 6
#define WS 392

typedef float v2f __attribute__((ext_vector_type(2)));
typedef float v4f __attribute__((ext_vector_type(4)));

__device__ __forceinline__ float readlane_f(float v, int l) {
    return __int_as_float(__builtin_amdgcn_readlane(__float_as_int(v), l));
}
// DPP wave shift-right by 1: dst lane i = src lane i-1, lane 0 = 0 (bound_ctrl).
__device__ __forceinline__ float wave_shr1_f(float v) {
    return __int_as_float(__builtin_amdgcn_mov_dpp(__float_as_int(v), 0x138, 0xf, 0xf, true));
}
// update_dpp with old=0: masked/out-of-range lanes contribute 0.
template<int CTRL, int RM>
__device__ __forceinline__ float dpp0_f(float v) {
    return __int_as_float(__builtin_amdgcn_update_dpp(0, __float_as_int(v), CTRL, RM, 0xf, true));
}
// 64-lane inclusive prefix sum (classic GCN DPP scan: 12 VALU, once per chunk).
__device__ __forceinline__ float wave_iscan_add(float v) {
    v += dpp0_f<0x111, 0xf>(v);   // row_shr:1
    v += dpp0_f<0x112, 0xf>(v);   // row_shr:2
    v += dpp0_f<0x114, 0xf>(v);   // row_shr:4
    v += dpp0_f<0x118, 0xf>(v);   // row_shr:8
    v += dpp0_f<0x142, 0xa>(v);   // row_bcast:15 -> rows 1,3
    v += dpp0_f<0x143, 0xc>(v);   // row_bcast:31 -> rows 2,3
    return v;
}

// R15: LDS-pipe decongestion. R14's VALU cuts were neutral -> kernel is bound by
// the per-CU LDS pipe (8 blocks/CU x ~384 per-lane ds_read_b128 gathers each).
// Fix: (a) producer wave reads its weight vectors from a GLOBAL copy of wtr in
// d_ws (L1-resident, 6.3 KB, shared by all blocks on a CU) -> 160 of 240 b128
// gathers move from the LDS pipe to the parallel vector-memory/L1 pipe; step
// wave keeps the LDS copy (80 gathers) to balance the two pipes. (b) spec-loop
// deposits paired into b64 writes (384 -> 192 LDS write ops). Everything else
// (spec/replay semantics, barriers, far-field math) verbatim R14.
__global__ void flif_prep(const float* __restrict__ W, float* __restrict__ wg) {
    for (int k = threadIdx.x; k < 4 * WS; k += 256) {
        const int r = k / WS, kk = k - r * WS;
        const int i = (kk ^ 1) + r;                 // pair-swap within aligned float4s
        wg[k] = (i <= 382) ? W[4998 - i] : 0.0f;
    }
}

__global__ __launch_bounds__(128, 4)
void flif_kernel(const float* __restrict__ I_old, const float* __restrict__ W,
                 const float* __restrict__ WG,
                 float* __restrict__ out, float cm1, float c2, float c3, int Stot)
{
    const int tid  = threadIdx.x;
    const int wid  = tid >> 6;
    const int lane = tid & 63;
    const int s    = blockIdx.x;

    __shared__ __align__(16) float wtr[4 * WS];     // wtr[r][kk] = wt[(kk^1)+r] (pair-swapped)
    __shared__ __align__(16) float dbuf[T_STEPS];   // delta history
    __shared__ float accs[2][CH];                   // g>=2 partial handoff

    for (int k = tid; k < 4 * WS; k += 128) {
        const int r = k / WS, kk = k - r * WS;
        const int i = (kk ^ 1) + r;                 // pair-swap within aligned float4s
        wtr[k] = (i <= 382) ? W[4998 - i] : 0.0f;
    }
    ((float*)accs)[tid] = 0.0f;
    __syncthreads();

    const int rl = lane & 3;
    const int woff = rl * WS + (lane - rl);

    if (wid == 1) {
        // ---- far-field producer wave (g>=2, source-major): weights via L1 ----
        const float* wlp = (WG ? WG : (const float*)wtr) + woff;
        v2f A2 = {0.0f, 0.0f}, A3 = {0.0f, 0.0f}, A4 = {0.0f, 0.0f}, A5 = {0.0f, 0.0f};
        #pragma unroll
        for (int c = 0; c < NCH; ++c) {
            if (c >= 1 && c <= 4) {
                const int src = c - 1;
                const float* dp = dbuf + src * CH;
                #pragma unroll
                for (int k = 0; k <= 60; k += 4) {
                    const v4f d4 = *reinterpret_cast<const v4f*>(dp + k);
                    #pragma unroll
                    for (int t = c + 1; t <= 5; ++t) {
                        const int g = t - src;
                        const v4f w4 = *reinterpret_cast<const v4f*>(wlp + (g * 64 - k - 4));
                        v2f& At = (t == 2) ? A2 : (t == 3) ? A3 : (t == 4) ? A4 : A5;
                        At = d4.xy * w4.zw + At;    // v_pk_fma_f32 (pair-swapped table)
                        At = d4.zw * w4.xy + At;
                    }
                }
                const v2f hv = (c == 1) ? A2 : (c == 2) ? A3 : (c == 3) ? A4 : A5;
                accs[(c + 1) & 1][lane] = hv.x + hv.y;
            }
            __syncthreads();
        }
        return;
    }

    // -------- step-loop wave (wid == 0) --------
    const float* wlpS = wtr + woff;                 // step wave keeps LDS weights
    const float* Irow = I_old + (size_t)s * T_STEPS;
    float Inext = Irow[lane];
    const float w0seed = (lane >= 1) ? W[4999 - lane] : 0.0f;   // wr[lane] (exact-path march)
    const float wr1n = -W[4998];                                 // -wr[1]
    const float b1 = cm1 - W[4998];                              // cm1 - wr[1]
    const float b2 = cm1 - W[4997];                              // cm1 - wr[2]
    const float w2seed = (lane >= 1) ? (cm1 - W[4999 - lane]) : 0.0f;  // spec scatter weight

    float Vcs = 0.0f;       // uniform chunk-entry V
    float rvprev = 0.0f;    // uniform reset term from previous chunk end
    float tcs[NCH], spks[NCH];

    for (int c = 0; c < NCH; ++c) {
        const int cb = c * CH;
        const float Ic = Inext;
        if (c + 1 < NCH) Inext = Irow[cb + CH + lane];

        // ---- far field: g>=2 partial from producer + g=1 pass (LDS weights) ----
        float acc = (c == 0) ? 0.0f : accs[c & 1][lane];
        if (c >= 1) {
            const float* dp = dbuf + (c - 1) * CH;
            v2f a2 = {0.0f, 0.0f};
            #pragma unroll
            for (int m0 = 60; m0 >= 0; m0 -= 4) {
                const v4f d4 = *reinterpret_cast<const v4f*>(dp + (60 - m0));
                const v4f w4 = *reinterpret_cast<const v4f*>(wlpS + m0);
                a2 = d4.xy * w4.zw + a2;            // v_pk_fma_f32
                a2 = d4.zw * w4.xy + a2;
            }
            acc += a2.x + a2.y;
        }

        const float u0 = fmaf(c3, Ic, c2) - acc;    // exact-basis t0 (saved for fallback)
        const float Vs = Vcs;
        float tc;
        float Vend;

        // ---------- speculative no-spike pass: serial cycle = 1 fma ----------
        {
            float u, Pq0, Pq1, w2;
            float dm1 = 0.0f, dm2 = 0.0f;
            if (c == 0) {
                // exact steps 0,1 (spike at 0, V1-rule at 1); Vcs = 0 so S == V
                const float V0 = -90.0f;
                const float wf = wave_shr1_f(w0seed);        // wr[lane-1]
                const float I1 = readlane_f(Ic, 1);
                const float V1 = fmaf(0.005f, (I1 / 0.025f) - V0, V0);
                const float d1 = V1 - V0;
                const float ue = fmaf(-wf, d1, u0);          // exact scatter of d_1
                u = fmaf(cm1, V1, ue);                       // + cm1*V_pre constant
                *reinterpret_cast<float2*>(&dbuf[0]) = make_float2(0.0f, d1);
                Pq0 = readlane_f(u, 2);                      // complete: taps are 0
                Pq1 = readlane_f(u, 3);
                w2 = wave_shr1_f(wave_shr1_f(w2seed));       // aligned for scattering d_2
                #pragma unroll
                for (int i = 2; i < CH; ++i) {
                    const float x  = fmaf(b2, dm2, (i & 1) ? Pq1 : Pq0);
                    const float dn = fmaf(b1, dm1, x);       // [the only serial cycle]
                    const float nf = readlane_f(u, (i + 2) & 63);   // BEFORE scatter
                    if (i & 1) Pq1 = nf; else Pq0 = nf;
                    u = fmaf(w2, dn, u);                     // scatter (cm1 - wr[.])*d
                    w2 = wave_shr1_f(w2);
                    if (i & 1)                               // paired b64 deposit
                        *reinterpret_cast<float2*>(&dbuf[i - 1]) = make_float2(dm1, dn);
                    dm2 = dm1; dm1 = dn;
                }
                const float dl = dbuf[lane];
                tc = -90.0f + wave_iscan_add(dl);            // per-lane V via scan
                Vend = readlane_f(tc, 63);
            } else {
                u = fmaf(cm1, Vcs, u0);                      // + cm1*V_cs constant
                Pq0 = readlane_f(u, 0) + rvprev;             // chunk-boundary reset carry
                Pq1 = readlane_f(u, 1);
                w2 = w2seed;
                #pragma unroll
                for (int i = 0; i < CH; ++i) {
                    const float x  = fmaf(b2, dm2, (i & 1) ? Pq1 : Pq0);
                    const float dn = fmaf(b1, dm1, x);
                    const float nf = readlane_f(u, (i + 2) & 63);
                    if (i & 1) Pq1 = nf; else Pq0 = nf;
                    u = fmaf(w2, dn, u);
                    w2 = wave_shr1_f(w2);
                    if (i & 1)                               // paired b64 deposit
                        *reinterpret_cast<float2*>(&dbuf[cb + i - 1]) = make_float2(dm1, dn);
                    dm2 = dm1; dm1 = dn;
                }
                const float dl = dbuf[cb + lane];
                tc = Vcs + wave_iscan_add(dl);               // absolutize per-lane V
                Vend = readlane_f(tc, 63);
            }
        }

        // ---------- margin check: any V near threshold -> exact replay ----------
        bool replayed = false;
        if (__any(tc > -50.5f)) {
            replayed = true;
            float V, d, b, P, w;
            float tcf = 0.0f;
            float uf = u0;
            if (c == 0) {
                V = -90.0f;
                if (lane == 0) tcf = V;
                w = wave_shr1_f(w0seed);
                const float I1 = readlane_f(Ic, 1);
                const float V1 = fmaf(0.005f, (I1 / 0.025f) - V, V);
                const float d1 = V1 - V;
                P = readlane_f(uf, 2);
                uf = fmaf(-w, d1, uf);
                w = wave_shr1_f(w);
                if (lane == 1) tcf = V1;
                V = V1; d = d1;
                b = fmaf(cm1, V, (V > -50.0f) ? -20.0f : 0.0f);
                #pragma unroll
                for (int i = 2; i < CH; ++i) {
                    const float t = fmaf(wr1n, d, P);
                    d = t + b;
                    P = readlane_f(uf, (i + 1) & 63);
                    V = V + d;
                    const float rv = (V > -50.0f) ? -20.0f : 0.0f;
                    b = fmaf(cm1, V, rv);
                    uf = fmaf(-w, d, uf);
                    w = wave_shr1_f(w);
                    tcf = (lane == i) ? V : tcf;
                }
            } else {
                V = Vcs; d = 0.0f;
                b = fmaf(cm1, Vcs, rvprev);
                w = w0seed;
                P = readlane_f(uf, 0);
                #pragma unroll
                for (int i = 0; i < CH; ++i) {
                    const float t = fmaf(wr1n, d, P);
                    d = t + b;
                    P = readlane_f(uf, (i + 1) & 63);
                    V = V + d;
                    const float rv = (V > -50.0f) ? -20.0f : 0.0f;
                    b = fmaf(cm1, V, rv);
                    uf = fmaf(-w, d, uf);
                    w = wave_shr1_f(w);
                    tcf = (lane == i) ? V : tcf;
                }
            }
            tc = tcf; Vend = V;
        }
        rvprev = (Vend > -50.0f) ? -20.0f : 0.0f;

        // ---- chunk epilogue: prev-V per lane -> spike; dbuf rewrite on replay ----
        float prev = __shfl_up(tc, 1);
        if (lane == 0) prev = Vs;
        spks[c] = (prev > -50.0f) ? 1.0f : 0.0f;
        if (replayed) {
            float dd = tc - prev;
            if (c == 0 && lane == 0) dd = 0.0f;              // delta_0 excluded by reference
            dbuf[cb + lane] = dd;                            // exact deltas overwrite spec
        }
        tcs[c] = tc;
        Vcs = Vend;
        __syncthreads();                                     // publish dbuf / consume accs
    }

    // ---- deferred global stores ----
    float* out_spk = out + (size_t)s * T_STEPS;
    float* out_trc = out + (size_t)Stot * T_STEPS + (size_t)s * T_STEPS;
    #pragma unroll
    for (int c = 0; c < NCH; ++c) {
        out_spk[c * CH + lane] = spks[c];
        out_trc[c * CH + lane] = tcs[c];
    }
}

extern "C" void kernel_launch(void* const* d_in, const int* in_sizes, int n_in,
                              void* d_out, int out_size, void* d_ws, size_t ws_size,
                              hipStream_t stream) {
    const float* I = (const float*)d_in[0];
    const float* W = (const float*)d_in[1];
    float* out = (float*)d_out;
    const int S = in_sizes[0] / T_STEPS;   // 2048

    const double COEF = std::pow(0.1, 0.15) * std::tgamma(1.85) / 0.5;
    const float c3  = (float)COEF;                     // COEF
    const float cm1 = (float)(-COEF * 0.025);          // c1 - 1 = -COEF*GL
    const float c2  = (float)(COEF * 0.025 * -70.0);   // COEF*GL*VL

    float* wg = (ws_size >= (size_t)(4 * WS) * sizeof(float)) ? (float*)d_ws : nullptr;
    if (wg) flif_prep<<<1, 256, 0, stream>>>(W, wg);
    flif_kernel<<<S, 128, 0, stream>>>(I, W, wg, out, cm1, c2, c3, S);
}

// Round 3
// 72.874 us; speedup vs baseline: 1.2227x; 1.2227x over previous
//
#include <hip/hip_runtime.h>
#include <cmath>

#define T_STEPS 384
#define CH 64
#define NCH 6
#define WS 392

typedef float v2f __attribute__((ext_vector_type(2)));
typedef float v4f __attribute__((ext_vector_type(4)));

__device__ __forceinline__ float readlane_f(float v, int l) {
    return __int_as_float(__builtin_amdgcn_readlane(__float_as_int(v), l));
}
// DPP wave shift-right by 1: dst lane i = src lane i-1, lane 0 = 0 (bound_ctrl).
__device__ __forceinline__ float wave_shr1_f(float v) {
    return __int_as_float(__builtin_amdgcn_mov_dpp(__float_as_int(v), 0x138, 0xf, 0xf, true));
}
// update_dpp with old=0: masked/out-of-range lanes contribute 0.
template<int CTRL, int RM>
__device__ __forceinline__ float dpp0_f(float v) {
    return __int_as_float(__builtin_amdgcn_update_dpp(0, __float_as_int(v), CTRL, RM, 0xf, true));
}
// 64-lane inclusive prefix sum (classic GCN DPP scan: 12 VALU, once per chunk).
__device__ __forceinline__ float wave_iscan_add(float v) {
    v += dpp0_f<0x111, 0xf>(v);   // row_shr:1
    v += dpp0_f<0x112, 0xf>(v);   // row_shr:2
    v += dpp0_f<0x114, 0xf>(v);   // row_shr:4
    v += dpp0_f<0x118, 0xf>(v);   // row_shr:8
    v += dpp0_f<0x142, 0xa>(v);   // row_bcast:15 -> rows 1,3
    v += dpp0_f<0x143, 0xc>(v);   // row_bcast:31 -> rows 2,3
    return v;
}

// R16: eliminate (not relocate) the repeated LDS weight gathers. R15 proved the
// global/L1 path is worse per-op; R16 register-caches the loop-invariant weight
// vectors instead: step wave caches all 16 v4f of gap-1 (kills 80 gathers/block),
// producer caches gap-2 (kills 64 of 160). Far-field accumulators split into
// dual chains (half the dependent-fma latency per tile). No prep kernel; wtr
// back in LDS for gaps 3-5. Spec/replay semantics verbatim R14.
__global__ __launch_bounds__(128, 4)
void flif_kernel(const float* __restrict__ I_old, const float* __restrict__ W,
                 float* __restrict__ out, float cm1, float c2, float c3, int Stot)
{
    const int tid  = threadIdx.x;
    const int wid  = tid >> 6;
    const int lane = tid & 63;
    const int s    = blockIdx.x;

    __shared__ __align__(16) float wtr[4 * WS];     // wtr[r][kk] = wt[(kk^1)+r] (pair-swapped)
    __shared__ __align__(16) float dbuf[T_STEPS];   // delta history
    __shared__ float accs[2][CH];                   // g>=2 partial handoff

    for (int k = tid; k < 4 * WS; k += 128) {
        const int r = k / WS, kk = k - r * WS;
        const int i = (kk ^ 1) + r;                 // pair-swap within aligned float4s
        wtr[k] = (i <= 382) ? W[4998 - i] : 0.0f;
    }
    ((float*)accs)[tid] = 0.0f;
    __syncthreads();

    const int rl = lane & 3;
    const float* wlp = wtr + rl * WS + (lane - rl);

    if (wid == 1) {
        // ---- far-field producer wave (g>=2, source-major) ----
        // gap-2 weight vectors register-cached (one-time 16 gathers, reused 4x6).
        v4f wc2[16];
        #pragma unroll
        for (int j = 0; j < 16; ++j)
            wc2[j] = *reinterpret_cast<const v4f*>(wlp + 64 + 4 * j);

        v2f A2a = {0.f,0.f}, A2b = {0.f,0.f}, A3a = {0.f,0.f}, A3b = {0.f,0.f};
        v2f A4a = {0.f,0.f}, A4b = {0.f,0.f}, A5a = {0.f,0.f}, A5b = {0.f,0.f};
        #pragma unroll
        for (int c = 0; c < NCH; ++c) {
            if (c >= 1 && c <= 4) {
                const int src = c - 1;
                const float* dp = dbuf + src * CH;
                #pragma unroll
                for (int k = 0; k <= 60; k += 4) {
                    const v4f d4 = *reinterpret_cast<const v4f*>(dp + k);
                    #pragma unroll
                    for (int t = c + 1; t <= 5; ++t) {
                        const int g = t - src;
                        const v4f w4 = (g == 2) ? wc2[(60 - k) >> 2]
                            : *reinterpret_cast<const v4f*>(wlp + (g * 64 - k - 4));
                        v2f& Aa = (t == 2) ? A2a : (t == 3) ? A3a : (t == 4) ? A4a : A5a;
                        v2f& Ab = (t == 2) ? A2b : (t == 3) ? A3b : (t == 4) ? A4b : A5b;
                        Aa = d4.xy * w4.zw + Aa;    // v_pk_fma_f32, dual chains
                        Ab = d4.zw * w4.xy + Ab;
                    }
                }
                const v2f hv = (c == 1) ? (A2a + A2b) : (c == 2) ? (A3a + A3b)
                             : (c == 3) ? (A4a + A4b) : (A5a + A5b);
                accs[(c + 1) & 1][lane] = hv.x + hv.y;
            }
            __syncthreads();
        }
        return;
    }

    // -------- step-loop wave (wid == 0) --------
    // gap-1 weight vectors register-cached (one-time 16 gathers, reused 5x).
    v4f wc1[16];
    #pragma unroll
    for (int j = 0; j < 16; ++j)
        wc1[j] = *reinterpret_cast<const v4f*>(wlp + 4 * j);

    const float* Irow = I_old + (size_t)s * T_STEPS;
    float Inext = Irow[lane];
    const float w0seed = (lane >= 1) ? W[4999 - lane] : 0.0f;   // wr[lane] (exact-path march)
    const float wr1n = -W[4998];                                 // -wr[1]
    const float b1 = cm1 - W[4998];                              // cm1 - wr[1]
    const float b2 = cm1 - W[4997];                              // cm1 - wr[2]
    const float w2seed = (lane >= 1) ? (cm1 - W[4999 - lane]) : 0.0f;  // spec scatter weight

    float Vcs = 0.0f;       // uniform chunk-entry V
    float rvprev = 0.0f;    // uniform reset term from previous chunk end
    float tcs[NCH], spks[NCH];

    for (int c = 0; c < NCH; ++c) {
        const int cb = c * CH;
        const float Ic = Inext;
        if (c + 1 < NCH) Inext = Irow[cb + CH + lane];

        // ---- far field: g>=2 partial from producer + g=1 pass (reg weights) ----
        float acc = (c == 0) ? 0.0f : accs[c & 1][lane];
        if (c >= 1) {
            const float* dp = dbuf + (c - 1) * CH;
            v2f a2 = {0.0f, 0.0f}, a3 = {0.0f, 0.0f};
            #pragma unroll
            for (int m0 = 60; m0 >= 0; m0 -= 4) {
                const v4f d4 = *reinterpret_cast<const v4f*>(dp + (60 - m0));
                const v4f w4 = wc1[m0 >> 2];
                a2 = d4.xy * w4.zw + a2;            // v_pk_fma_f32, dual chains
                a3 = d4.zw * w4.xy + a3;
            }
            acc += (a2.x + a2.y) + (a3.x + a3.y);
        }

        const float u0 = fmaf(c3, Ic, c2) - acc;    // exact-basis t0 (saved for fallback)
        const float Vs = Vcs;
        float tc;
        float Vend;

        // ---------- speculative no-spike pass: serial cycle = 1 fma ----------
        {
            float u, Pq0, Pq1, w2;
            float dm1 = 0.0f, dm2 = 0.0f;
            if (c == 0) {
                // exact steps 0,1 (spike at 0, V1-rule at 1); Vcs = 0 so S == V
                const float V0 = -90.0f;
                const float wf = wave_shr1_f(w0seed);        // wr[lane-1]
                const float I1 = readlane_f(Ic, 1);
                const float V1 = fmaf(0.005f, (I1 / 0.025f) - V0, V0);
                const float d1 = V1 - V0;
                const float ue = fmaf(-wf, d1, u0);          // exact scatter of d_1
                u = fmaf(cm1, V1, ue);                       // + cm1*V_pre constant
                *reinterpret_cast<float2*>(&dbuf[0]) = make_float2(0.0f, d1);
                Pq0 = readlane_f(u, 2);                      // complete: taps are 0
                Pq1 = readlane_f(u, 3);
                w2 = wave_shr1_f(wave_shr1_f(w2seed));       // aligned for scattering d_2
                #pragma unroll
                for (int i = 2; i < CH; ++i) {
                    const float x  = fmaf(b2, dm2, (i & 1) ? Pq1 : Pq0);
                    const float dn = fmaf(b1, dm1, x);       // [the only serial cycle]
                    const float nf = readlane_f(u, (i + 2) & 63);   // BEFORE scatter
                    if (i & 1) Pq1 = nf; else Pq0 = nf;
                    u = fmaf(w2, dn, u);                     // scatter (cm1 - wr[.])*d
                    w2 = wave_shr1_f(w2);
                    if (i & 1)                               // paired b64 deposit
                        *reinterpret_cast<float2*>(&dbuf[i - 1]) = make_float2(dm1, dn);
                    dm2 = dm1; dm1 = dn;
                }
                const float dl = dbuf[lane];
                tc = -90.0f + wave_iscan_add(dl);            // per-lane V via scan
                Vend = readlane_f(tc, 63);
            } else {
                u = fmaf(cm1, Vcs, u0);                      // + cm1*V_cs constant
                Pq0 = readlane_f(u, 0) + rvprev;             // chunk-boundary reset carry
                Pq1 = readlane_f(u, 1);
                w2 = w2seed;
                #pragma unroll
                for (int i = 0; i < CH; ++i) {
                    const float x  = fmaf(b2, dm2, (i & 1) ? Pq1 : Pq0);
                    const float dn = fmaf(b1, dm1, x);
                    const float nf = readlane_f(u, (i + 2) & 63);
                    if (i & 1) Pq1 = nf; else Pq0 = nf;
                    u = fmaf(w2, dn, u);
                    w2 = wave_shr1_f(w2);
                    if (i & 1)                               // paired b64 deposit
                        *reinterpret_cast<float2*>(&dbuf[cb + i - 1]) = make_float2(dm1, dn);
                    dm2 = dm1; dm1 = dn;
                }
                const float dl = dbuf[cb + lane];
                tc = Vcs + wave_iscan_add(dl);               // absolutize per-lane V
                Vend = readlane_f(tc, 63);
            }
        }

        // ---------- margin check: any V near threshold -> exact replay ----------
        bool replayed = false;
        if (__any(tc > -50.5f)) {
            replayed = true;
            float V, d, b, P, w;
            float tcf = 0.0f;
            float uf = u0;
            if (c == 0) {
                V = -90.0f;
                if (lane == 0) tcf = V;
                w = wave_shr1_f(w0seed);
                const float I1 = readlane_f(Ic, 1);
                const float V1 = fmaf(0.005f, (I1 / 0.025f) - V, V);
                const float d1 = V1 - V;
                P = readlane_f(uf, 2);
                uf = fmaf(-w, d1, uf);
                w = wave_shr1_f(w);
                if (lane == 1) tcf = V1;
                V = V1; d = d1;
                b = fmaf(cm1, V, (V > -50.0f) ? -20.0f : 0.0f);
                #pragma unroll
                for (int i = 2; i < CH; ++i) {
                    const float t = fmaf(wr1n, d, P);
                    d = t + b;
                    P = readlane_f(uf, (i + 1) & 63);
                    V = V + d;
                    const float rv = (V > -50.0f) ? -20.0f : 0.0f;
                    b = fmaf(cm1, V, rv);
                    uf = fmaf(-w, d, uf);
                    w = wave_shr1_f(w);
                    tcf = (lane == i) ? V : tcf;
                }
            } else {
                V = Vcs; d = 0.0f;
                b = fmaf(cm1, Vcs, rvprev);
                w = w0seed;
                P = readlane_f(uf, 0);
                #pragma unroll
                for (int i = 0; i < CH; ++i) {
                    const float t = fmaf(wr1n, d, P);
                    d = t + b;
                    P = readlane_f(uf, (i + 1) & 63);
                    V = V + d;
                    const float rv = (V > -50.0f) ? -20.0f : 0.0f;
                    b = fmaf(cm1, V, rv);
                    uf = fmaf(-w, d, uf);
                    w = wave_shr1_f(w);
                    tcf = (lane == i) ? V : tcf;
                }
            }
            tc = tcf; Vend = V;
        }
        rvprev = (Vend > -50.0f) ? -20.0f : 0.0f;

        // ---- chunk epilogue: prev-V per lane -> spike; dbuf rewrite on replay ----
        float prev = __shfl_up(tc, 1);
        if (lane == 0) prev = Vs;
        spks[c] = (prev > -50.0f) ? 1.0f : 0.0f;
        if (replayed) {
            float dd = tc - prev;
            if (c == 0 && lane == 0) dd = 0.0f;              // delta_0 excluded by reference
            dbuf[cb + lane] = dd;                            // exact deltas overwrite spec
        }
        tcs[c] = tc;
        Vcs = Vend;
        __syncthreads();                                     // publish dbuf / consume accs
    }

    // ---- deferred global stores ----
    float* out_spk = out + (size_t)s * T_STEPS;
    float* out_trc = out + (size_t)Stot * T_STEPS + (size_t)s * T_STEPS;
    #pragma unroll
    for (int c = 0; c < NCH; ++c) {
        out_spk[c * CH + lane] = spks[c];
        out_trc[c * CH + lane] = tcs[c];
    }
}

extern "C" void kernel_launch(void* const* d_in, const int* in_sizes, int n_in,
                              void* d_out, int out_size, void* d_ws, size_t ws_size,
                              hipStream_t stream) {
    const float* I = (const float*)d_in[0];
    const float* W = (const float*)d_in[1];
    float* out = (float*)d_out;
    const int S = in_sizes[0] / T_STEPS;   // 2048

    const double COEF = std::pow(0.1, 0.15) * std::tgamma(1.85) / 0.5;
    const float c3  = (float)COEF;                     // COEF
    const float cm1 = (float)(-COEF * 0.025);          // c1 - 1 = -COEF*GL
    const float c2  = (float)(COEF * 0.025 * -70.0);   // COEF*GL*VL

    flif_kernel<<<S, 128, 0, stream>>>(I, W, out, cm1, c2, c3, S);
}